// Round 11
// baseline (368.841 us; speedup 1.0000x reference)
//
#include <hip/hip_runtime.h>
#include <hip/hip_bf16.h>
#include <stdint.h>

#define HID 256
#define BM  64
#define LDA 68    // As row stride in ushorts (lp_mono only)
#define LDC 264   // C staging row stride in ushorts (measured zero-conflict)

typedef __bf16 bf16x8 __attribute__((ext_vector_type(8)));
typedef float  f32x4  __attribute__((ext_vector_type(4)));

__device__ __forceinline__ ushort f2bf(float x) {
    union { float f; uint32_t u; } v; v.f = x;
    uint32_t u = v.u;
    uint32_t r = u + 0x7fffu + ((u >> 16) & 1u);   // RNE
    return (ushort)(r >> 16);
}

__device__ __forceinline__ uint32_t pack2bf(float a, float b) {
    union { float f; uint32_t u; } ua, ub;
    ua.f = a; ub.f = b;
    return __builtin_amdgcn_perm(ub.u + 0x8000u, ua.u + 0x8000u, 0x07060302u);
}

__device__ __forceinline__ float uaf(uint32_t x) {
    union { uint32_t u; float f; } c; c.u = x; return c.f;
}

// W1[512][256] fp32 -> Wt4 bf16, layout [grp = k/8][n 0..255][j = k%8]
// B-fragment loads are then 16B/lane contiguous (256-B runs per quad).
__global__ void conv_w1(const float* __restrict__ W1, ushort* __restrict__ Wt4) {
    __shared__ ushort tr[32][33];
    const int bk = blockIdx.x >> 3;   // k-tile 0..15
    const int bn = blockIdx.x & 7;    // n-tile 0..7
    const int t  = threadIdx.x;
    #pragma unroll
    for (int i = 0; i < 4; ++i) {
        int e = t + 256 * i; int r = e >> 5, cc = e & 31;
        tr[cc][r] = f2bf(W1[(size_t)(bk * 32 + r) * HID + bn * 32 + cc]);
    }
    __syncthreads();
    #pragma unroll
    for (int i = 0; i < 4; ++i) {
        int e = t + 256 * i; int rn = e >> 5, ck = e & 31;
        int k = bk * 32 + ck;
        int grp = k >> 3;
        int j   = k & 7;
        int n   = bn * 32 + rn;
        Wt4[((size_t)grp * HID + n) * 8 + j] = tr[rn][ck];
    }
}

// -------- phase 1: dense per-node GEMM  u = emb @ W1half  (bf16 out) --------
// ONE WAVE = ONE 16x256 TILE. No barriers, no cross-wave LDS, no shared
// staging: the six 4-wave barrier-coupled variants (r0/r4/r5/r7/r8) were
// invariant at 104-110us regardless of K-loop micro-structure — the block
// structure itself (lockstep waves + ~3 resident blocks) capped HBM
// concurrency at ~2 TB/s (r2's accidental high-residency run hit 3.55).
// Here the MFMA A-fragment is loaded DIRECTLY from global (lane(q,cl) reads
// 8 consecutive fp32 of row cl at k=c*32+q*8 — wave pattern: 16 rows x 128B
// contiguous segments) and converted in-register (VALU was 90% idle). B
// streams from L2-resident Wt4. Every wave pipelines independently; 12
// waves/CU issue HBM loads continuously. Epilogue: wave-PRIVATE LDS quarter
// (no s_barrier; explicit lgkmcnt(0) — rule 18: compiler can't see
// cross-lane LDS deps) then proven coalesced uint4 stores (r7: direct
// scalar stores inflate WRITE via RMW).
__global__ __launch_bounds__(256, 3)
void node_gemm(const float* __restrict__ emb0, const float* __restrict__ emb1,
               const ushort* __restrict__ Wt4,
               ushort* __restrict__ u0, ushort* __restrict__ u1,
               int n0, int n1, int nt0, int ntiles) {
    __shared__ __align__(16) ushort Cw[4][16 * LDC];   // 33792 B, wave-private quarters

    const int wave = threadIdx.x >> 6, lane = threadIdx.x & 63;
    const int q = lane >> 4, cl = lane & 15;
    const int tile = blockIdx.x * 4 + wave;
    if (tile >= ntiles) return;

    const int tb  = (tile >= nt0) ? 1 : 0;
    const float* emb = tb ? emb1 : emb0;
    ushort*      uo  = tb ? u1 : u0;
    const int    n   = tb ? n1 : n0;
    const int    base = (tile - tb * nt0) * 16;

    int arow = base + cl; if (arow > n - 1) arow = n - 1;   // clamp (dup rows OK)
    const float* ap = emb + (size_t)arow * HID + q * 8;

    f32x4 acc[16] = {};

    #pragma unroll
    for (int c = 0; c < 8; ++c) {
        // ---- B fragments for k-step c: grp = tb*32 + c*4 + q, k = grp*8+j
        const ushort* bb = Wt4 + ((size_t)(tb * 32 + c * 4 + q) * HID + cl) * 8;
        bf16x8 bfr[16];
        #pragma unroll
        for (int ni = 0; ni < 16; ++ni)
            bfr[ni] = *reinterpret_cast<const bf16x8*>(bb + ni * 16 * 8);
        // ---- A fragment direct from global: A[cl][c*32 + q*8 + 0..7]
        float4 a0 = *reinterpret_cast<const float4*>(ap + c * 32);
        float4 a1 = *reinterpret_cast<const float4*>(ap + c * 32 + 4);
        union { uint32_t u[4]; bf16x8 v; } af;
        af.u[0] = pack2bf(a0.x, a0.y); af.u[1] = pack2bf(a0.z, a0.w);
        af.u[2] = pack2bf(a1.x, a1.y); af.u[3] = pack2bf(a1.z, a1.w);
        // ---- 16 MFMAs (N = 256)
        #pragma unroll
        for (int ni = 0; ni < 16; ++ni)
            acc[ni] = __builtin_amdgcn_mfma_f32_16x16x32_bf16(
                af.v, bfr[ni], acc[ni], 0, 0, 0);
    }

    // ---- wave-private epilogue (no s_barrier) ----
    ushort* cw = Cw[wave];
    #pragma unroll
    for (int ni = 0; ni < 16; ++ni)
        #pragma unroll
        for (int r = 0; r < 4; ++r)
            cw[(q * 4 + r) * LDC + ni * 16 + cl] = f2bf(acc[ni][r]);
    asm volatile("s_waitcnt lgkmcnt(0)" ::: "memory");   // cross-lane LDS RAW
    __builtin_amdgcn_sched_barrier(0);
    #pragma unroll
    for (int i = 0; i < 8; ++i) {
        int f = lane + 64 * i;                 // 0..511
        int row = f >> 5, unit = f & 31;       // 16 rows x 32 16B-units
        int grow = base + row;
        if (grow < n) {
            uint4 w = *reinterpret_cast<const uint4*>(&cw[row * LDC + unit * 8]);
            *reinterpret_cast<uint4*>(uo + (size_t)grow * HID + unit * 8) = w;
        }
    }
}

// -------- phase 2: per-edge  logit = relu(u[s]+v[d]+b1) . W2 + b2 --------
// T14 async-stage: ping-pong batches (gA/gB, static indexing) — issue batch
// b+1's index+row gathers BEFORE processing batch b, hiding L2/L3 gather
// latency (~600cy) under the shuffle/FMA processing (~1100cy).
#define EB 8
__global__ __launch_bounds__(256, 4)
void lp_edge(const ushort* __restrict__ u, const ushort* __restrict__ v,
             const int* __restrict__ eli,
             const float* __restrict__ b1, const float* __restrict__ W2,
             const float* __restrict__ b2, float* __restrict__ out,
             int E, int nwaves) {
    const int lane = threadIdx.x & 63;
    const int half = lane >> 5, sub = lane & 31;
    const int wid  = blockIdx.x * (blockDim.x >> 6) + (threadIdx.x >> 6);

    float b1v[8], w2v[8];
    {
        const float4* p1 = reinterpret_cast<const float4*>(b1 + sub * 8);
        const float4* p2 = reinterpret_cast<const float4*>(W2 + sub * 8);
        float4 a = p1[0], b = p1[1], c = p2[0], d = p2[1];
        b1v[0]=a.x; b1v[1]=a.y; b1v[2]=a.z; b1v[3]=a.w;
        b1v[4]=b.x; b1v[5]=b.y; b1v[6]=b.z; b1v[7]=b.w;
        w2v[0]=c.x; w2v[1]=c.y; w2v[2]=c.z; w2v[3]=c.w;
        w2v[4]=d.x; w2v[5]=d.y; w2v[6]=d.z; w2v[7]=d.w;
    }
    const float bias2 = b2[0];
    const ushort* tab  = half ? v : u;
    const int*    idxp = eli + (size_t)half * E;

    auto gather = [&](int b, uint4* gg) {
        #pragma unroll
        for (int j = 0; j < EB; ++j) {
            int e = b + j; if (e > E - 1) e = E - 1;
            int row = idxp[e];
            gg[j] = *reinterpret_cast<const uint4*>(tab + (size_t)row * HID + sub * 8);
        }
    };
    auto process = [&](const uint4* gg, int b) {
        float res = 0.f;
        #pragma unroll
        for (int j = 0; j < EB; ++j) {
            uint32_t pd[4], gd[4] = { gg[j].x, gg[j].y, gg[j].z, gg[j].w };
            #pragma unroll
            for (int c = 0; c < 4; ++c) pd[c] = (uint32_t)__shfl_xor((int)gd[c], 32);
            float acc = 0.f;
            #pragma unroll
            for (int c = 0; c < 4; ++c) {
                float a0 = uaf(gd[c] << 16), a1 = uaf(gd[c] & 0xffff0000u);
                float o0 = uaf(pd[c] << 16), o1 = uaf(pd[c] & 0xffff0000u);
                float h0 = fmaxf(a0 + o0 + b1v[2 * c], 0.f);
                float h1 = fmaxf(a1 + o1 + b1v[2 * c + 1], 0.f);
                acc = fmaf(h0, w2v[2 * c], acc);
                acc = fmaf(h1, w2v[2 * c + 1], acc);
            }
            #pragma unroll
            for (int m = 1; m <= 16; m <<= 1) acc += __shfl_xor(acc, m);
            if (half == 0 && sub == j) res = acc + bias2;
        }
        int e = b + sub;
        if (half == 0 && sub < EB && e < E) out[e] = res;
    };

    const int step = nwaves * EB;
    int base = wid * EB;
    uint4 gA[EB], gB[EB];
    gather(base, gA);
    while (base < E) {
        gather(base + step, gB);     // prefetch next batch (clamped; harmless past end)
        process(gA, base);
        base += step;
        if (base >= E) break;
        gather(base + step, gA);
        process(gB, base);
        base += step;
    }
}

// -------- fallback (monolithic) if ws is too small --------
__global__ __launch_bounds__(256, 3)
void lp_mono(const float* __restrict__ es, const float* __restrict__ ed,
             const int* __restrict__ eli, const float* __restrict__ W1,
             const float* __restrict__ b1, const float* __restrict__ W2,
             const float* __restrict__ b2,
             float* __restrict__ out, int E) {
    __shared__ __align__(16) ushort As[2][BM * LDA];
    __shared__ int   sIdx[2][BM];
    __shared__ float hred[4][BM];

    const int t = threadIdx.x, e0 = blockIdx.x * BM;
    const int wave = t >> 6, lane = t & 63, q = lane >> 4, cl = lane & 15;

    if (t < 2 * BM) {
        int which = t >> 6, e = t & 63;
        int ge = e0 + e; if (ge > E - 1) ge = E - 1;
        sIdx[which][e] = eli[which * E + ge];
    }
    __syncthreads();

    int ge_[2], go_[2], rsrc[2], rdst[2];
    #pragma unroll
    for (int i = 0; i < 2; ++i) {
        int c2 = t + 256 * i;
        ge_[i] = c2 >> 3; go_[i] = c2 & 7;
        rsrc[i] = sIdx[0][ge_[i]];
        rdst[i] = sIdx[1][ge_[i]];
    }
    float4 g0[2], g1[2];
    auto gather = [&](int c) {
        const float* tab = (c < 4) ? es : ed;
        #pragma unroll
        for (int i = 0; i < 2; ++i) {
            int row = (c < 4) ? rsrc[i] : rdst[i];
            const float* p = tab + (size_t)row * HID + (c & 3) * 64 + go_[i] * 8;
            g0[i] = *reinterpret_cast<const float4*>(p);
            g1[i] = *reinterpret_cast<const float4*>(p + 4);
        }
    };
    auto cvstore = [&](int buf) {
        #pragma unroll
        for (int i = 0; i < 2; ++i) {
            uint4 v;
            v.x = pack2bf(g0[i].x, g0[i].y); v.y = pack2bf(g0[i].z, g0[i].w);
            v.z = pack2bf(g1[i].x, g1[i].y); v.w = pack2bf(g1[i].z, g1[i].w);
            *reinterpret_cast<uint4*>(&As[buf][ge_[i] * LDA + go_[i] * 8]) = v;
        }
    };
    gather(0); cvstore(0); __syncthreads();
    f32x4 acc[4][4] = {};
    #pragma unroll
    for (int c = 0; c < 8; ++c) {
        const int cur = c & 1;
        if (c < 7) gather(c + 1);
        #pragma unroll
        for (int ks = 0; ks < 2; ++ks) {
            bf16x8 af[4], bfr[4];
            #pragma unroll
            for (int mi = 0; mi < 4; ++mi)
                af[mi] = *reinterpret_cast<const bf16x8*>(
                    &As[cur][(mi * 16 + cl) * LDA + ks * 32 + q * 8]);
            #pragma unroll
            for (int ni = 0; ni < 4; ++ni) {
                int nn = wave * 64 + ni * 16 + cl;
                union { ushort s[8]; bf16x8 v; } u;
                #pragma unroll
                for (int j = 0; j < 8; ++j)
                    u.s[j] = f2bf(W1[(size_t)(c * 64 + ks * 32 + q * 8 + j) * HID + nn]);
                bfr[ni] = u.v;
            }
            #pragma unroll
            for (int mi = 0; mi < 4; ++mi)
                #pragma unroll
                for (int ni = 0; ni < 4; ++ni)
                    acc[mi][ni] = __builtin_amdgcn_mfma_f32_16x16x32_bf16(
                        af[mi], bfr[ni], acc[mi][ni], 0, 0, 0);
        }
        if (c < 7) { cvstore(cur ^ 1); __syncthreads(); }
    }
    float b1v[4], w2v[4];
    #pragma unroll
    for (int ni = 0; ni < 4; ++ni) {
        int col = wave * 64 + ni * 16 + cl;
        b1v[ni] = b1[col]; w2v[ni] = W2[col];
    }
    #pragma unroll
    for (int mi = 0; mi < 4; ++mi) {
        #pragma unroll
        for (int r = 0; r < 4; ++r) {
            float s = 0.f;
            #pragma unroll
            for (int ni = 0; ni < 4; ++ni) {
                float h = acc[mi][ni][r] + b1v[ni];
                h = fmaxf(h, 0.f);
                s += h * w2v[ni];
            }
            s += __shfl_xor(s, 1); s += __shfl_xor(s, 2);
            s += __shfl_xor(s, 4); s += __shfl_xor(s, 8);
            if (cl == 0) hred[wave][mi * 16 + q * 4 + r] = s;
        }
    }
    __syncthreads();
    if (t < BM) {
        int ge = e0 + t;
        if (ge < E)
            out[ge] = hred[0][t] + hred[1][t] + hred[2][t] + hred[3][t] + b2[0];
    }
}

extern "C" void kernel_launch(void* const* d_in, const int* in_sizes, int n_in,
                              void* d_out, int out_size, void* d_ws, size_t ws_size,
                              hipStream_t stream) {
    const float* emb_src = (const float*)d_in[0];
    const float* emb_dst = (const float*)d_in[1];
    const int*   eli     = (const int*)d_in[2];
    const float* W1      = (const float*)d_in[3];
    const float* b1      = (const float*)d_in[4];
    const float* W2      = (const float*)d_in[5];
    const float* b2      = (const float*)d_in[6];
    float*       out     = (float*)d_out;

    const int E   = in_sizes[2] / 2;
    const int n0n = in_sizes[0] / HID;
    const int n1n = in_sizes[1] / HID;

    const size_t wtB = (size_t)2 * HID * 2 * HID * sizeof(ushort);   // 256 KB
    const size_t uB  = (size_t)n0n * HID * sizeof(ushort);
    const size_t vB  = (size_t)n1n * HID * sizeof(ushort);

    ushort* Wt4 = (ushort*)d_ws;
    ushort* u0  = (ushort*)((char*)d_ws + wtB);
    ushort* u1  = (ushort*)((char*)d_ws + wtB + uB);

    const int fullPath = ws_size >= wtB + uB + vB;

    if (fullPath) {
        conv_w1<<<128, 256, 0, stream>>>(W1, Wt4);
        const int nt0 = (n0n + 15) / 16;
        const int nt1 = (n1n + 15) / 16;
        const int ntiles = nt0 + nt1;
        const int nblk = (ntiles + 3) / 4;
        node_gemm<<<nblk, 256, 0, stream>>>(emb_src, emb_dst, Wt4,
                                            u0, u1, n0n, n1n, nt0, ntiles);
        const int eb = 2048;
        lp_edge<<<eb, 256, 0, stream>>>(u0, u1, eli, b1, W2, b2, out, E, eb * 4);
    } else {
        const int nb = (E + BM - 1) / BM;
        lp_mono<<<nb, 256, 0, stream>>>(emb_src, emb_dst, eli, W1,
                                        b1, W2, b2, out, E);
    }
}

// Round 13
// 335.208 us; speedup vs baseline: 1.1003x; 1.1003x over previous
//
#include <hip/hip_runtime.h>
#include <hip/hip_bf16.h>
#include <stdint.h>

#define HID 256
#define BM  32    // 32-row tiles: acc[2][4]=32 AGPRs -> unified reg total ~100
#define LDA 68    // As row stride in ushorts (34 dwords == 2 mod 32: measured zero-conflict)
#define LDC 264   // Cs row stride in ushorts

typedef __bf16 bf16x8 __attribute__((ext_vector_type(8)));
typedef float  f32x4  __attribute__((ext_vector_type(4)));

__device__ __forceinline__ ushort f2bf(float x) {
    union { float f; uint32_t u; } v; v.f = x;
    uint32_t u = v.u;
    uint32_t r = u + 0x7fffu + ((u >> 16) & 1u);   // RNE
    return (ushort)(r >> 16);
}

__device__ __forceinline__ uint32_t pack2bf(float a, float b) {
    union { float f; uint32_t u; } ua, ub;
    ua.f = a; ub.f = b;
    return __builtin_amdgcn_perm(ub.u + 0x8000u, ua.u + 0x8000u, 0x07060302u);
}

__device__ __forceinline__ float uaf(uint32_t x) {
    union { uint32_t u; float f; } c; c.u = x; return c.f;
}

// Raw workgroup barrier WITHOUT the vmcnt(0) drain __syncthreads forces.
// LDS hazards only need lgkmcnt(0); in-flight global loads survive (T4).
__device__ __forceinline__ void wavebar() {
    asm volatile("s_waitcnt lgkmcnt(0)" ::: "memory");
    __builtin_amdgcn_sched_barrier(0);
    __builtin_amdgcn_s_barrier();
    __builtin_amdgcn_sched_barrier(0);
}

// W1[512][256] fp32 -> Wt4 bf16, layout [grp = k/8][n 0..255][j = k%8]
// B-fragment loads are then 16B/lane contiguous (256-B runs per quad).
__global__ void conv_w1(const float* __restrict__ W1, ushort* __restrict__ Wt4) {
    __shared__ ushort tr[32][33];
    const int bk = blockIdx.x >> 3;   // k-tile 0..15
    const int bn = blockIdx.x & 7;    // n-tile 0..7
    const int t  = threadIdx.x;
    #pragma unroll
    for (int i = 0; i < 4; ++i) {
        int e = t + 256 * i; int r = e >> 5, cc = e & 31;
        tr[cc][r] = f2bf(W1[(size_t)(bk * 32 + r) * HID + bn * 32 + cc]);
    }
    __syncthreads();
    #pragma unroll
    for (int i = 0; i < 4; ++i) {
        int e = t + 256 * i; int rn = e >> 5, ck = e & 31;
        int k = bk * 32 + ck;
        int grp = k >> 3;
        int j   = k & 7;
        int n   = bn * 32 + rn;
        Wt4[((size_t)grp * HID + n) * 8 + j] = tr[rn][ck];
    }
}

// -------- phase 1: dense per-node GEMM  u = emb @ W1half  (bf16 out) --------
// RESIDENCY FIX (r11 synthesis): gfx950's unified VGPR/AGPR file means the
// acc[4][4]=64-AGPR accumulator pinned every BM=64 variant at 3-4 waves/SIMD
// (VGPR 72-80 + AGPR 64 = 136-144 -> class 3; matches measured 28-38% occ in
// r0/r5/r8/r11). r2's accidental 104-reg spill run hit 5 waves/SIMD and
// 3.55 TB/s — the machine delivers BW when residency rises. BM=32 halves the
// accumulator (acc[2][4]=32 AGPR): total ~100 regs -> launch_bounds(256,5)
// (cap 102, no spill pressure) gives >=5 waves/SIMD, ~1.7x prior residency.
// Pipeline unchanged from r8 (measured-correct): 2-deep register A-gather,
// raw barriers (no vmcnt drain), LDA=68 zero-conflict LDS, Cs uint4 epilogue.
// One dispatch per emb table (diagnostic: halves dispatch time so lp_edge
// finally surfaces in the top-5 counters).
__global__ __launch_bounds__(256, 5)
void node_gemm(const float* __restrict__ emb, const ushort* __restrict__ Wt4,
               ushort* __restrict__ uo, int n, int kofs) {
    __shared__ __align__(16) union {
        ushort As[2][BM * LDA];   // 8704 B (K-loop)
        ushort Cs[BM * LDC];      // 16896 B (epilogue)
    } sm;

    const int t  = threadIdx.x;
    const int e0 = blockIdx.x * BM;

    const int wave = t >> 6, lane = t & 63, q = lane >> 4, cl = lane & 15;

    // staging: thread t -> row = t>>3 (0..31), seg8 = t&7 (8-float unit)
    const int r0 = t >> 3, seg8 = t & 7;
    int rcl = e0 + r0; if (rcl > n - 1) rcl = n - 1;
    const float* abase = emb + (size_t)rcl * HID + seg8 * 8;
    const int    sbase = r0 * LDA + seg8 * 8;

    float4 ga[2], gb[2];
    auto gload = [&](float4* g, int c) {
        g[0] = *reinterpret_cast<const float4*>(abase + c * 64);
        g[1] = *reinterpret_cast<const float4*>(abase + c * 64 + 4);
    };
    auto cvst = [&](const float4* g, int buf) {
        uint2 v0, v1;
        v0.x = pack2bf(g[0].x, g[0].y); v0.y = pack2bf(g[0].z, g[0].w);
        v1.x = pack2bf(g[1].x, g[1].y); v1.y = pack2bf(g[1].z, g[1].w);
        *reinterpret_cast<uint2*>(&sm.As[buf][sbase])     = v0;
        *reinterpret_cast<uint2*>(&sm.As[buf][sbase + 4]) = v1;
    };

    f32x4 acc[2][4] = {};
    bf16x8 bfr[2][4];
    auto bload = [&](int c) {
        #pragma unroll
        for (int ks = 0; ks < 2; ++ks) {
            const ushort* bb = Wt4 + ((size_t)(kofs + c * 8 + ks * 4 + q) * HID) * 8;
            #pragma unroll
            for (int ni = 0; ni < 4; ++ni)
                bfr[ks][ni] = *reinterpret_cast<const bf16x8*>(
                    bb + (wave * 64 + ni * 16 + cl) * 8);
        }
    };
    auto mm = [&](int buf) {
        #pragma unroll
        for (int ks = 0; ks < 2; ++ks) {
            #pragma unroll
            for (int mi = 0; mi < 2; ++mi) {
                bf16x8 af = *reinterpret_cast<const bf16x8*>(
                    &sm.As[buf][(mi * 16 + cl) * LDA + ks * 32 + q * 8]);
                #pragma unroll
                for (int ni = 0; ni < 4; ++ni)
                    acc[mi][ni] = __builtin_amdgcn_mfma_f32_16x16x32_bf16(
                        af, bfr[ks][ni], acc[mi][ni], 0, 0, 0);
            }
        }
    };

    // ---- prologue: chunk0 staged; chunk1 issued and left in flight ----
    gload(ga, 0);
    cvst(ga, 0);           // waits chunk0 only
    gload(ga, 1);          // in flight across the raw barrier
    wavebar();

    // ---- K-loop, fully unrolled, 2-deep pipeline, raw barriers ----
    bload(0); gload(gb, 2);
    mm(0);
    cvst(ga, 1);
    wavebar();
    bload(1); gload(ga, 3);
    mm(1);
    cvst(gb, 0);
    wavebar();
    bload(2);
    mm(0);
    cvst(ga, 1);
    wavebar();
    bload(3);
    mm(1);

    __syncthreads();   // all As reads done before Cs overwrites the union

    // ---- epilogue: scatter -> barrier -> coalesced uint4 store ----
    #pragma unroll
    for (int mi = 0; mi < 2; ++mi)
        #pragma unroll
        for (int ni = 0; ni < 4; ++ni)
            #pragma unroll
            for (int r = 0; r < 4; ++r)
                sm.Cs[(mi * 16 + q * 4 + r) * LDC + wave * 64 + ni * 16 + cl] =
                    f2bf(acc[mi][ni][r]);
    __syncthreads();

    // 32 rows x 32 16B-units = 1024 units; f = t + 256*i
    #pragma unroll
    for (int i = 0; i < 4; ++i) {
        int f = t + 256 * i;
        int row = f >> 5, unit = f & 31;
        int grow = e0 + row;
        if (grow < n) {
            uint4 w = *reinterpret_cast<const uint4*>(&sm.Cs[row * LDC + unit * 8]);
            *reinterpret_cast<uint4*>(uo + (size_t)grow * HID + unit * 8) = w;
        }
    }
}

// -------- phase 2: per-edge  logit = relu(u[s]+v[d]+b1) . W2 + b2 --------
// T14 async-stage: ping-pong batches (gA/gB, static indexing) — issue batch
// b+1's index+row gathers BEFORE processing batch b, hiding L2/L3 gather
// latency (~600cy) under the shuffle/FMA processing (~1100cy).
#define EB 8
__global__ __launch_bounds__(256, 4)
void lp_edge(const ushort* __restrict__ u, const ushort* __restrict__ v,
             const int* __restrict__ eli,
             const float* __restrict__ b1, const float* __restrict__ W2,
             const float* __restrict__ b2, float* __restrict__ out,
             int E, int nwaves) {
    const int lane = threadIdx.x & 63;
    const int half = lane >> 5, sub = lane & 31;
    const int wid  = blockIdx.x * (blockDim.x >> 6) + (threadIdx.x >> 6);

    float b1v[8], w2v[8];
    {
        const float4* p1 = reinterpret_cast<const float4*>(b1 + sub * 8);
        const float4* p2 = reinterpret_cast<const float4*>(W2 + sub * 8);
        float4 a = p1[0], b = p1[1], c = p2[0], d = p2[1];
        b1v[0]=a.x; b1v[1]=a.y; b1v[2]=a.z; b1v[3]=a.w;
        b1v[4]=b.x; b1v[5]=b.y; b1v[6]=b.z; b1v[7]=b.w;
        w2v[0]=c.x; w2v[1]=c.y; w2v[2]=c.z; w2v[3]=c.w;
        w2v[4]=d.x; w2v[5]=d.y; w2v[6]=d.z; w2v[7]=d.w;
    }
    const float bias2 = b2[0];
    const ushort* tab  = half ? v : u;
    const int*    idxp = eli + (size_t)half * E;

    auto gather = [&](int b, uint4* gg) {
        #pragma unroll
        for (int j = 0; j < EB; ++j) {
            int e = b + j; if (e > E - 1) e = E - 1;
            int row = idxp[e];
            gg[j] = *reinterpret_cast<const uint4*>(tab + (size_t)row * HID + sub * 8);
        }
    };
    auto process = [&](const uint4* gg, int b) {
        float res = 0.f;
        #pragma unroll
        for (int j = 0; j < EB; ++j) {
            uint32_t pd[4], gd[4] = { gg[j].x, gg[j].y, gg[j].z, gg[j].w };
            #pragma unroll
            for (int c = 0; c < 4; ++c) pd[c] = (uint32_t)__shfl_xor((int)gd[c], 32);
            float acc = 0.f;
            #pragma unroll
            for (int c = 0; c < 4; ++c) {
                float a0 = uaf(gd[c] << 16), a1 = uaf(gd[c] & 0xffff0000u);
                float o0 = uaf(pd[c] << 16), o1 = uaf(pd[c] & 0xffff0000u);
                float h0 = fmaxf(a0 + o0 + b1v[2 * c], 0.f);
                float h1 = fmaxf(a1 + o1 + b1v[2 * c + 1], 0.f);
                acc = fmaf(h0, w2v[2 * c], acc);
                acc = fmaf(h1, w2v[2 * c + 1], acc);
            }
            #pragma unroll
            for (int m = 1; m <= 16; m <<= 1) acc += __shfl_xor(acc, m);
            if (half == 0 && sub == j) res = acc + bias2;
        }
        int e = b + sub;
        if (half == 0 && sub < EB && e < E) out[e] = res;
    };

    const int step = nwaves * EB;
    int base = wid * EB;
    uint4 gA[EB], gB[EB];
    gather(base, gA);
    while (base < E) {
        gather(base + step, gB);     // prefetch next batch (clamped; harmless past end)
        process(gA, base);
        base += step;
        if (base >= E) break;
        gather(base + step, gA);
        process(gB, base);
        base += step;
    }
}

// -------- fallback (monolithic) if ws is too small --------
__global__ __launch_bounds__(256, 3)
void lp_mono(const float* __restrict__ es, const float* __restrict__ ed,
             const int* __restrict__ eli, const float* __restrict__ W1,
             const float* __restrict__ b1, const float* __restrict__ W2,
             const float* __restrict__ b2,
             float* __restrict__ out, int E) {
    __shared__ __align__(16) ushort As[2][64 * LDA];
    __shared__ int   sIdx[2][64];
    __shared__ float hred[4][64];

    const int t = threadIdx.x, e0 = blockIdx.x * 64;
    const int wave = t >> 6, lane = t & 63, q = lane >> 4, cl = lane & 15;

    if (t < 128) {
        int which = t >> 6, e = t & 63;
        int ge = e0 + e; if (ge > E - 1) ge = E - 1;
        sIdx[which][e] = eli[which * E + ge];
    }
    __syncthreads();

    int ge_[2], go_[2], rsrc[2], rdst[2];
    #pragma unroll
    for (int i = 0; i < 2; ++i) {
        int c2 = t + 256 * i;
        ge_[i] = c2 >> 3; go_[i] = c2 & 7;
        rsrc[i] = sIdx[0][ge_[i]];
        rdst[i] = sIdx[1][ge_[i]];
    }
    float4 g0[2], g1[2];
    auto gather = [&](int c) {
        const float* tab = (c < 4) ? es : ed;
        #pragma unroll
        for (int i = 0; i < 2; ++i) {
            int row = (c < 4) ? rsrc[i] : rdst[i];
            const float* p = tab + (size_t)row * HID + (c & 3) * 64 + go_[i] * 8;
            g0[i] = *reinterpret_cast<const float4*>(p);
            g1[i] = *reinterpret_cast<const float4*>(p + 4);
        }
    };
    auto cvstore = [&](int buf) {
        #pragma unroll
        for (int i = 0; i < 2; ++i) {
            uint4 v;
            v.x = pack2bf(g0[i].x, g0[i].y); v.y = pack2bf(g0[i].z, g0[i].w);
            v.z = pack2bf(g1[i].x, g1[i].y); v.w = pack2bf(g1[i].z, g1[i].w);
            *reinterpret_cast<uint4*>(&As[buf][ge_[i] * LDA + go_[i] * 8]) = v;
        }
    };
    gather(0); cvstore(0); __syncthreads();
    f32x4 acc[4][4] = {};
    #pragma unroll
    for (int c = 0; c < 8; ++c) {
        const int cur = c & 1;
        if (c < 7) gather(c + 1);
        #pragma unroll
        for (int ks = 0; ks < 2; ++ks) {
            bf16x8 af[4], bfr[4];
            #pragma unroll
            for (int mi = 0; mi < 4; ++mi)
                af[mi] = *reinterpret_cast<const bf16x8*>(
                    &As[cur][(mi * 16 + cl) * LDA + ks * 32 + q * 8]);
            #pragma unroll
            for (int ni = 0; ni < 4; ++ni) {
                int nn = wave * 64 + ni * 16 + cl;
                union { ushort s[8]; bf16x8 v; } u;
                #pragma unroll
                for (int j = 0; j < 8; ++j)
                    u.s[j] = f2bf(W1[(size_t)(c * 64 + ks * 32 + q * 8 + j) * HID + nn]);
                bfr[ni] = u.v;
            }
            #pragma unroll
            for (int mi = 0; mi < 4; ++mi)
                #pragma unroll
                for (int ni = 0; ni < 4; ++ni)
                    acc[mi][ni] = __builtin_amdgcn_mfma_f32_16x16x32_bf16(
                        af[mi], bfr[ni], acc[mi][ni], 0, 0, 0);
        }
        if (c < 7) { cvstore(cur ^ 1); __syncthreads(); }
    }
    float b1v[4], w2v[4];
    #pragma unroll
    for (int ni = 0; ni < 4; ++ni) {
        int col = wave * 64 + ni * 16 + cl;
        b1v[ni] = b1[col]; w2v[ni] = W2[col];
    }
    #pragma unroll
    for (int mi = 0; mi < 4; ++mi) {
        #pragma unroll
        for (int r = 0; r < 4; ++r) {
            float s = 0.f;
            #pragma unroll
            for (int ni = 0; ni < 4; ++ni) {
                float h = acc[mi][ni][r] + b1v[ni];
                h = fmaxf(h, 0.f);
                s += h * w2v[ni];
            }
            s += __shfl_xor(s, 1); s += __shfl_xor(s, 2);
            s += __shfl_xor(s, 4); s += __shfl_xor(s, 8);
            if (cl == 0) hred[wave][mi * 16 + q * 4 + r] = s;
        }
    }
    __syncthreads();
    if (t < 64) {
        int ge = e0 + t;
        if (ge < E)
            out[ge] = hred[0][t] + hred[1][t] + hred[2][t] + hred[3][t] + b2[0];
    }
}

extern "C" void kernel_launch(void* const* d_in, const int* in_sizes, int n_in,
                              void* d_out, int out_size, void* d_ws, size_t ws_size,
                              hipStream_t stream) {
    const float* emb_src = (const float*)d_in[0];
    const float* emb_dst = (const float*)d_in[1];
    const int*   eli     = (const int*)d_in[2];
    const float* W1      = (const float*)d_in[3];
    const float* b1      = (const float*)d_in[4];
    const float* W2      = (const float*)d_in[5];
    const float* b2      = (const float*)d_in[6];
    float*       out     = (float*)d_out;

    const int E   = in_sizes[2] / 2;
    const int n0n = in_sizes[0] / HID;
    const int n1n = in_sizes[1] / HID;

    const size_t wtB = (size_t)2 * HID * 2 * HID * sizeof(ushort);   // 256 KB
    const size_t uB  = (size_t)n0n * HID * sizeof(ushort);
    const size_t vB  = (size_t)n1n * HID * sizeof(ushort);

    ushort* Wt4 = (ushort*)d_ws;
    ushort* u0  = (ushort*)((char*)d_ws + wtB);
    ushort* u1  = (ushort*)((char*)d_ws + wtB + uB);

    const int fullPath = ws_size >= wtB + uB + vB;

    if (fullPath) {
        conv_w1<<<128, 256, 0, stream>>>(W1, Wt4);
        const int nb0 = (n0n + BM - 1) / BM;
        const int nb1 = (n1n + BM - 1) / BM;
        node_gemm<<<nb0, 256, 0, stream>>>(emb_src, Wt4, u0, n0n, 0);
        node_gemm<<<nb1, 256, 0, stream>>>(emb_dst, Wt4, u1, n1n, 32);
        const int eb = 2048;
        lp_edge<<<eb, 256, 0, stream>>>(u0, u1, eli, b1, W2, b2, out, E, eb * 4);
    } else {
        const int nb = (E + 63) / 64;
        lp_mono<<<nb, 256, 0, stream>>>(emb_src, emb_dst, eli, W1,
                                        b1, W2, b2, out, E);
    }
}